// Round 1
// baseline (1257.995 us; speedup 1.0000x reference)
//
#include <hip/hip_runtime.h>
#include <math.h>

#define BB 2
#define NN 50000
#define FF 256
#define UU 256
#define FED 128
#define TT 3
#define EE 131072

// ---------------- Kernel 1: src_gated = features @ W_gate ----------------
// Block: 256 threads, 32 rows x 256 u. features tile staged in LDS.
__global__ __launch_bounds__(256) void k_srcgate(const float* __restrict__ feats,
                                                 const float* __restrict__ Wg,
                                                 float* __restrict__ sg) {
    const int r0 = blockIdx.x * 32;
    const int u  = threadIdx.x;
    __shared__ float ft[32][FF];
#pragma unroll
    for (int i = 0; i < 32; ++i) ft[i][u] = feats[(size_t)(r0 + i) * FF + u];
    __syncthreads();

    float acc[32];
#pragma unroll
    for (int e = 0; e < 32; ++e) acc[e] = 0.f;

    for (int k = 0; k < FF; k += 4) {
        const float w0 = Wg[(k + 0) * UU + u];
        const float w1 = Wg[(k + 1) * UU + u];
        const float w2 = Wg[(k + 2) * UU + u];
        const float w3 = Wg[(k + 3) * UU + u];
#pragma unroll
        for (int e = 0; e < 32; ++e) {
            const float4 f = *reinterpret_cast<const float4*>(&ft[e][k]);
            acc[e] += f.x * w0 + f.y * w1 + f.z * w2 + f.w * w3;
        }
    }
#pragma unroll
    for (int e = 0; e < 32; ++e) sg[(size_t)(r0 + e) * UU + u] = acc[e];
}

// ---------------- Kernel 2: per-edge gate/value + gather + scatter --------
// Block: 256 threads, 32 edges of one edge-type. Thread owns one u column.
template <bool USE_WS>
__global__ __launch_bounds__(256) void k_edges(const int* __restrict__ eidx,
                                               const float* __restrict__ efeat,
                                               const float* __restrict__ Wge,
                                               const float* __restrict__ Wde,
                                               const float* __restrict__ bd,
                                               const float* __restrict__ sgws,
                                               const float* __restrict__ feats,
                                               const float* __restrict__ Wg,
                                               float* __restrict__ out) {
    const int tilesPerT = EE / 32;
    const int t  = blockIdx.x / tilesPerT;
    const int e0 = (blockIdx.x % tilesPerT) * 32;
    const int u  = threadIdx.x;

    __shared__ float ef[32][FED];
    __shared__ int   idx[32];

    {
        const float* src = efeat + ((size_t)t * EE + e0) * FED;
#pragma unroll
        for (int i = 0; i < 16; ++i) {
            const int elem = i * 256 + u;
            ef[elem >> 7][elem & 127] = src[elem];
        }
    }
    if (u < 32) idx[u] = eidx[t * EE + e0 + u];
    __syncthreads();

    const float* Wgt = Wge + (size_t)t * FED * UU;
    const float* Wdt = Wde + (size_t)t * FED * UU;

    float accg[32], accv[32];
#pragma unroll
    for (int e = 0; e < 32; ++e) { accg[e] = 0.f; accv[e] = 0.f; }

    for (int k = 0; k < FED; k += 4) {
        const float g0 = Wgt[(k + 0) * UU + u];
        const float g1 = Wgt[(k + 1) * UU + u];
        const float g2 = Wgt[(k + 2) * UU + u];
        const float g3 = Wgt[(k + 3) * UU + u];
        const float d0 = Wdt[(k + 0) * UU + u];
        const float d1 = Wdt[(k + 1) * UU + u];
        const float d2 = Wdt[(k + 2) * UU + u];
        const float d3 = Wdt[(k + 3) * UU + u];
#pragma unroll
        for (int e = 0; e < 32; ++e) {
            const float4 f = *reinterpret_cast<const float4*>(&ef[e][k]);
            accg[e] += f.x * g0 + f.y * g1 + f.z * g2 + f.w * g3;
            accv[e] += f.x * d0 + f.y * d1 + f.z * d2 + f.w * d3;
        }
    }

    float sgv[32];
    if constexpr (USE_WS) {
#pragma unroll
        for (int e = 0; e < 32; ++e) sgv[e] = sgws[(size_t)idx[e] * UU + u];
    } else {
        // Fallback: compute gathered src_gated rows inline.
        __shared__ float ft[32][FF];
#pragma unroll
        for (int i = 0; i < 32; ++i) ft[i][u] = feats[(size_t)idx[i] * FF + u];
        __syncthreads();
        float sacc[32];
#pragma unroll
        for (int e = 0; e < 32; ++e) sacc[e] = 0.f;
        for (int k = 0; k < FF; k += 4) {
            const float w0 = Wg[(k + 0) * UU + u];
            const float w1 = Wg[(k + 1) * UU + u];
            const float w2 = Wg[(k + 2) * UU + u];
            const float w3 = Wg[(k + 3) * UU + u];
#pragma unroll
            for (int e = 0; e < 32; ++e) {
                const float4 f = *reinterpret_cast<const float4*>(&ft[e][k]);
                sacc[e] += f.x * w0 + f.y * w1 + f.z * w2 + f.w * w3;
            }
        }
#pragma unroll
        for (int e = 0; e < 32; ++e) sgv[e] = sacc[e];
    }

    const float bv = bd[t * UU + u];
#pragma unroll
    for (int e = 0; e < 32; ++e) {
        const float g   = 1.f / (1.f + __expf(-(sgv[e] + accg[e])));
        const float msg = (accv[e] + bv) * g;
        atomicAdd(&out[(size_t)idx[e] * UU + u], msg);
    }
}

extern "C" void kernel_launch(void* const* d_in, const int* in_sizes, int n_in,
                              void* d_out, int out_size, void* d_ws, size_t ws_size,
                              hipStream_t stream) {
    const float* feats = (const float*)d_in[0];
    const int*   eidx  = (const int*)d_in[1];
    const float* efeat = (const float*)d_in[2];
    const float* Wg    = (const float*)d_in[3];
    const float* Wge   = (const float*)d_in[4];
    const float* Wde   = (const float*)d_in[5];
    const float* bd    = (const float*)d_in[6];
    float* out = (float*)d_out;

    hipMemsetAsync(d_out, 0, (size_t)out_size * sizeof(float), stream);

    const size_t sg_bytes = (size_t)BB * NN * UU * sizeof(float);
    if (ws_size >= sg_bytes) {
        float* sg = (float*)d_ws;
        k_srcgate<<<(BB * NN) / 32, 256, 0, stream>>>(feats, Wg, sg);
        k_edges<true><<<TT * (EE / 32), 256, 0, stream>>>(eidx, efeat, Wge, Wde, bd,
                                                          sg, nullptr, nullptr, out);
    } else {
        k_edges<false><<<TT * (EE / 32), 256, 0, stream>>>(eidx, efeat, Wge, Wde, bd,
                                                           nullptr, feats, Wg, out);
    }
}

// Round 2
// 869.527 us; speedup vs baseline: 1.4468x; 1.4468x over previous
//
#include <hip/hip_runtime.h>
#include <hip/hip_bf16.h>
#include <math.h>

#define BBx 2
#define NNx 50000
#define M1 (BBx * NNx)   // 100000 node rows
#define FF 256
#define UU 256
#define FED 128
#define TT 3
#define EE 131072

typedef __attribute__((ext_vector_type(8))) short short8;
typedef __attribute__((ext_vector_type(4))) float f32x4;

static __device__ __forceinline__ ushort f2bf(float x) {
    union { float f; uint u; } c; c.f = x;
    const uint u = c.u;
    return (ushort)((u + 0x7FFFu + ((u >> 16) & 1u)) >> 16);  // RTNE
}
static __device__ __forceinline__ float bf2f(ushort h) {
    union { uint u; float f; } c; c.u = ((uint)h) << 16;
    return c.f;
}

// ---- prep: convert + transpose weights to bf16 [n][k] layouts in ws ----
__global__ __launch_bounds__(256) void k_prep(const float* __restrict__ Wg,
                                              const float* __restrict__ Wge,
                                              const float* __restrict__ Wde,
                                              short* __restrict__ WtG,
                                              short* __restrict__ WtGe,
                                              short* __restrict__ WtDe) {
    const int idx = blockIdx.x * 256 + threadIdx.x;  // 262144 total
    if (idx < 65536) {                               // W_gate: [256k][256n] -> [256n][256k]
        const int n = idx >> 8, k = idx & 255;
        WtG[n * 256 + k] = (short)f2bf(Wg[k * 256 + n]);
    } else {
        int j = idx - 65536;                         // 2*98304 for Wge/Wde
        const float* src = Wge;
        short* dst = WtGe;
        if (j >= 98304) { j -= 98304; src = Wde; dst = WtDe; }
        const int t = j >> 15, rem = j & 32767;      // 32768 per type
        const int n = rem >> 7, k = rem & 127;
        dst[t * 32768 + n * 128 + k] = (short)f2bf(src[t * 32768 + k * 256 + n]);
    }
}

// ---- Kernel 1: src_gated = features @ W_gate (bf16 MFMA), output bf16 ----
__global__ __launch_bounds__(256) void k1_srcgate(const float* __restrict__ feats,
                                                  const short* __restrict__ WtG,
                                                  ushort* __restrict__ sg) {
    __shared__ char As[32 * 512];  // 32 rows x 256 bf16, XOR-swizzled
    const int tid = threadIdx.x, lane = tid & 63, wid = tid >> 6;
    const int r0 = blockIdx.x * 32;

    const float* src = feats + (size_t)r0 * FF;
#pragma unroll
    for (int j = 0; j < 4; ++j) {
        const int chunk = j * 256 + tid;             // 1024 chunks of 8 floats
        const int row = chunk >> 5, kc = chunk & 31;
        const float4 f0 = *(const float4*)(src + row * FF + kc * 8);
        const float4 f1 = *(const float4*)(src + row * FF + kc * 8 + 4);
        short8 v;
        v[0]=(short)f2bf(f0.x); v[1]=(short)f2bf(f0.y); v[2]=(short)f2bf(f0.z); v[3]=(short)f2bf(f0.w);
        v[4]=(short)f2bf(f1.x); v[5]=(short)f2bf(f1.y); v[6]=(short)f2bf(f1.z); v[7]=(short)f2bf(f1.w);
        int byte = row * 512 + kc * 16;
        byte ^= (row & 7) << 4;
        *(short8*)(As + byte) = v;
    }
    __syncthreads();

    const int nb = wid * 64;
    f32x4 acc[2][4];
#pragma unroll
    for (int m = 0; m < 2; ++m)
#pragma unroll
        for (int n = 0; n < 4; ++n) acc[m][n] = (f32x4){0.f, 0.f, 0.f, 0.f};

    for (int ks = 0; ks < 8; ++ks) {
        short8 a[2];
#pragma unroll
        for (int m = 0; m < 2; ++m) {
            const int row = m * 16 + (lane & 15);
            int byte = row * 512 + ks * 64 + (lane >> 4) * 16;
            byte ^= (row & 7) << 4;
            a[m] = *(const short8*)(As + byte);
        }
#pragma unroll
        for (int n = 0; n < 4; ++n) {
            const int col = nb + n * 16 + (lane & 15);
            const short8 b = *(const short8*)(WtG + col * 256 + ks * 32 + (lane >> 4) * 8);
#pragma unroll
            for (int m = 0; m < 2; ++m)
                acc[m][n] = __builtin_amdgcn_mfma_f32_16x16x32_bf16(a[m], b, acc[m][n], 0, 0, 0);
        }
    }
#pragma unroll
    for (int m = 0; m < 2; ++m)
#pragma unroll
        for (int n = 0; n < 4; ++n) {
            const int col = nb + n * 16 + (lane & 15);
#pragma unroll
            for (int r = 0; r < 4; ++r) {
                const int row = m * 16 + (lane >> 4) * 4 + r;
                sg[(size_t)(r0 + row) * UU + col] = f2bf(acc[m][n][r]);
            }
        }
}

// ---- Kernel 2: per-type edge GEMMs (gate+value) + gather/sigmoid/scatter ----
__global__ __launch_bounds__(256) void k2_edges(const int* __restrict__ eidx,
                                                const float* __restrict__ efeat,
                                                const short* __restrict__ WtGe,
                                                const short* __restrict__ WtDe,
                                                const float* __restrict__ bd,
                                                const ushort* __restrict__ sg,
                                                float* __restrict__ out) {
    __shared__ char As[64 * 256];  // 64 edges x 128 bf16, XOR-swizzled
    __shared__ int idxs[64];
    const int tid = threadIdx.x, lane = tid & 63, wid = tid >> 6;
    const int t = blockIdx.y;
    const int e0 = blockIdx.x * 64;

    const float* src = efeat + ((size_t)t * EE + e0) * FED;
#pragma unroll
    for (int j = 0; j < 4; ++j) {
        const int chunk = j * 256 + tid;             // 1024 chunks of 8 floats
        const int row = chunk >> 4, kc = chunk & 15;
        const float4 f0 = *(const float4*)(src + row * FED + kc * 8);
        const float4 f1 = *(const float4*)(src + row * FED + kc * 8 + 4);
        short8 v;
        v[0]=(short)f2bf(f0.x); v[1]=(short)f2bf(f0.y); v[2]=(short)f2bf(f0.z); v[3]=(short)f2bf(f0.w);
        v[4]=(short)f2bf(f1.x); v[5]=(short)f2bf(f1.y); v[6]=(short)f2bf(f1.z); v[7]=(short)f2bf(f1.w);
        int byte = row * 256 + kc * 16;
        byte ^= (row & 7) << 4;
        *(short8*)(As + byte) = v;
    }
    if (tid < 64) idxs[tid] = eidx[t * EE + e0 + tid];
    __syncthreads();

    const short* Bg = WtGe + t * 32768;  // [256n][128k]
    const short* Bd = WtDe + t * 32768;
    const int nb = wid * 64;

    f32x4 accg[4][4], accv[4][4];
#pragma unroll
    for (int m = 0; m < 4; ++m)
#pragma unroll
        for (int n = 0; n < 4; ++n) {
            accg[m][n] = (f32x4){0.f, 0.f, 0.f, 0.f};
            accv[m][n] = (f32x4){0.f, 0.f, 0.f, 0.f};
        }

#pragma unroll
    for (int ks = 0; ks < 4; ++ks) {
        short8 a[4];
#pragma unroll
        for (int m = 0; m < 4; ++m) {
            const int row = m * 16 + (lane & 15);
            int byte = row * 256 + ks * 64 + (lane >> 4) * 16;
            byte ^= (row & 7) << 4;
            a[m] = *(const short8*)(As + byte);
        }
#pragma unroll
        for (int n = 0; n < 4; ++n) {
            const int col = nb + n * 16 + (lane & 15);
            const int koff = ks * 32 + (lane >> 4) * 8;
            const short8 bg = *(const short8*)(Bg + col * 128 + koff);
            const short8 bv = *(const short8*)(Bd + col * 128 + koff);
#pragma unroll
            for (int m = 0; m < 4; ++m) {
                accg[m][n] = __builtin_amdgcn_mfma_f32_16x16x32_bf16(a[m], bg, accg[m][n], 0, 0, 0);
                accv[m][n] = __builtin_amdgcn_mfma_f32_16x16x32_bf16(a[m], bv, accv[m][n], 0, 0, 0);
            }
        }
    }

    float bias[4];
#pragma unroll
    for (int n = 0; n < 4; ++n) bias[n] = bd[t * UU + nb + n * 16 + (lane & 15)];

#pragma unroll
    for (int m = 0; m < 4; ++m) {
        int node[4];
#pragma unroll
        for (int r = 0; r < 4; ++r) node[r] = idxs[m * 16 + (lane >> 4) * 4 + r];
#pragma unroll
        for (int n = 0; n < 4; ++n) {
            const int col = nb + n * 16 + (lane & 15);
#pragma unroll
            for (int r = 0; r < 4; ++r) {
                const float sgv = bf2f(sg[(size_t)node[r] * UU + col]);
                const float g = 1.f / (1.f + __expf(-(sgv + accg[m][n][r])));
                const float msg = (accv[m][n][r] + bias[n]) * g;
                atomicAdd(&out[(size_t)node[r] * UU + col], msg);
            }
        }
    }
}

extern "C" void kernel_launch(void* const* d_in, const int* in_sizes, int n_in,
                              void* d_out, int out_size, void* d_ws, size_t ws_size,
                              hipStream_t stream) {
    const float* feats = (const float*)d_in[0];
    const int*   eidx  = (const int*)d_in[1];
    const float* efeat = (const float*)d_in[2];
    const float* Wg    = (const float*)d_in[3];
    const float* Wge   = (const float*)d_in[4];
    const float* Wde   = (const float*)d_in[5];
    const float* bd    = (const float*)d_in[6];
    float* out = (float*)d_out;

    // ws layout: sg bf16 (51.2 MB) | WtG (128 KB) | WtGe (192 KB) | WtDe (192 KB)
    char* ws = (char*)d_ws;
    ushort* sg = (ushort*)ws;
    const size_t sg_bytes = (size_t)M1 * UU * sizeof(ushort);        // 51,200,000
    short* WtG  = (short*)(ws + sg_bytes);
    short* WtGe = (short*)(ws + sg_bytes + 131072);
    short* WtDe = (short*)(ws + sg_bytes + 131072 + 196608);

    hipMemsetAsync(d_out, 0, (size_t)out_size * sizeof(float), stream);

    k_prep<<<262144 / 256, 256, 0, stream>>>(Wg, Wge, Wde, WtG, WtGe, WtDe);
    k1_srcgate<<<M1 / 32, 256, 0, stream>>>(feats, WtG, sg);
    k2_edges<<<dim3(EE / 64, TT), 256, 0, stream>>>(eidx, efeat, WtGe, WtDe, bd,
                                                    (const ushort*)sg, out);
}

// Round 3
// 518.979 us; speedup vs baseline: 2.4240x; 1.6755x over previous
//
#include <hip/hip_runtime.h>
#include <math.h>

#define M1 100000
#define FF 256
#define UU 256
#define FED 128
#define TT 3
#define EE 131072
#define EPB 32   // edges per block in k2

typedef __attribute__((ext_vector_type(8))) short short8;
typedef __attribute__((ext_vector_type(4))) float f32x4;

static __device__ __forceinline__ ushort f2bf(float x) {
    union { float f; uint u; } c; c.f = x;
    const uint u = c.u;
    return (ushort)((u + 0x7FFFu + ((u >> 16) & 1u)) >> 16);  // RTNE
}
static __device__ __forceinline__ float bf2f(ushort h) {
    union { uint u; float f; } c; c.u = ((uint)h) << 16;
    return c.f;
}

// ---- prep: convert + transpose weights to bf16 [n][k] layouts in ws ----
__global__ __launch_bounds__(256) void k_prep(const float* __restrict__ Wg,
                                              const float* __restrict__ Wge,
                                              const float* __restrict__ Wde,
                                              short* __restrict__ WtG,
                                              short* __restrict__ WtGe,
                                              short* __restrict__ WtDe) {
    const int idx = blockIdx.x * 256 + threadIdx.x;  // 262144 total
    if (idx < 65536) {                               // W_gate: [256k][256n] -> [256n][256k]
        const int n = idx >> 8, k = idx & 255;
        WtG[n * 256 + k] = (short)f2bf(Wg[k * 256 + n]);
    } else {
        int j = idx - 65536;                         // 2*98304 for Wge/Wde
        const float* src = Wge;
        short* dst = WtGe;
        if (j >= 98304) { j -= 98304; src = Wde; dst = WtDe; }
        const int t = j >> 15, rem = j & 32767;      // 32768 per type
        const int n = rem >> 7, k = rem & 127;
        dst[t * 32768 + n * 128 + k] = (short)f2bf(src[t * 32768 + k * 256 + n]);
    }
}

// ---- Kernel 1: src_gated = features @ W_gate (bf16 MFMA), output bf16 ----
__global__ __launch_bounds__(256) void k1_srcgate(const float* __restrict__ feats,
                                                  const short* __restrict__ WtG,
                                                  ushort* __restrict__ sg) {
    __shared__ char As[32 * 512];  // 32 rows x 256 bf16, XOR-swizzled
    const int tid = threadIdx.x, lane = tid & 63, wid = tid >> 6;
    const int r0 = blockIdx.x * 32;

    const float* src = feats + (size_t)r0 * FF;
#pragma unroll
    for (int j = 0; j < 4; ++j) {
        const int chunk = j * 256 + tid;             // 1024 chunks of 8 floats
        const int row = chunk >> 5, kc = chunk & 31;
        const float4 f0 = *(const float4*)(src + row * FF + kc * 8);
        const float4 f1 = *(const float4*)(src + row * FF + kc * 8 + 4);
        short8 v;
        v[0]=(short)f2bf(f0.x); v[1]=(short)f2bf(f0.y); v[2]=(short)f2bf(f0.z); v[3]=(short)f2bf(f0.w);
        v[4]=(short)f2bf(f1.x); v[5]=(short)f2bf(f1.y); v[6]=(short)f2bf(f1.z); v[7]=(short)f2bf(f1.w);
        int byte = row * 512 + kc * 16;
        byte ^= (row & 7) << 4;
        *(short8*)(As + byte) = v;
    }
    __syncthreads();

    const int nb = wid * 64;
    f32x4 acc[2][4];
#pragma unroll
    for (int m = 0; m < 2; ++m)
#pragma unroll
        for (int n = 0; n < 4; ++n) acc[m][n] = (f32x4){0.f, 0.f, 0.f, 0.f};

    for (int ks = 0; ks < 8; ++ks) {
        short8 a[2];
#pragma unroll
        for (int m = 0; m < 2; ++m) {
            const int row = m * 16 + (lane & 15);
            int byte = row * 512 + ks * 64 + (lane >> 4) * 16;
            byte ^= (row & 7) << 4;
            a[m] = *(const short8*)(As + byte);
        }
#pragma unroll
        for (int n = 0; n < 4; ++n) {
            const int col = nb + n * 16 + (lane & 15);
            const short8 b = *(const short8*)(WtG + col * 256 + ks * 32 + (lane >> 4) * 8);
#pragma unroll
            for (int m = 0; m < 2; ++m)
                acc[m][n] = __builtin_amdgcn_mfma_f32_16x16x32_bf16(a[m], b, acc[m][n], 0, 0, 0);
        }
    }
#pragma unroll
    for (int m = 0; m < 2; ++m)
#pragma unroll
        for (int n = 0; n < 4; ++n) {
            const int col = nb + n * 16 + (lane & 15);
#pragma unroll
            for (int r = 0; r < 4; ++r) {
                const int row = m * 16 + (lane >> 4) * 4 + r;
                sg[(size_t)(r0 + row) * UU + col] = f2bf(acc[m][n][r]);
            }
        }
}

// ---- Kernel 2: per-type edge GEMMs (gate+value) + gather/sigmoid/scatter ----
// 32 edges per block; sg rows pre-gathered into LDS (coalesced) before MFMA.
__global__ __launch_bounds__(256, 4) void k2_edges(const int* __restrict__ eidx,
                                                   const float* __restrict__ efeat,
                                                   const short* __restrict__ WtGe,
                                                   const short* __restrict__ WtDe,
                                                   const float* __restrict__ bd,
                                                   const ushort* __restrict__ sg,
                                                   float* __restrict__ out) {
    __shared__ char As[EPB * 256];        // 32 edges x 128 bf16, XOR-swizzled
    __shared__ ushort sgl[EPB][260];      // gathered sg rows (+4 pad)
    __shared__ int idxs[EPB];
    const int tid = threadIdx.x, lane = tid & 63, wid = tid >> 6;
    const int t = blockIdx.y;
    const int e0 = blockIdx.x * EPB;

    const float* src = efeat + ((size_t)t * EE + e0) * FED;
#pragma unroll
    for (int j = 0; j < 2; ++j) {
        const int chunk = j * 256 + tid;             // 512 chunks of 8 floats
        const int row = chunk >> 4, kc = chunk & 15;
        const float4 f0 = *(const float4*)(src + row * FED + kc * 8);
        const float4 f1 = *(const float4*)(src + row * FED + kc * 8 + 4);
        short8 v;
        v[0]=(short)f2bf(f0.x); v[1]=(short)f2bf(f0.y); v[2]=(short)f2bf(f0.z); v[3]=(short)f2bf(f0.w);
        v[4]=(short)f2bf(f1.x); v[5]=(short)f2bf(f1.y); v[6]=(short)f2bf(f1.z); v[7]=(short)f2bf(f1.w);
        int byte = row * 256 + kc * 16;
        byte ^= (row & 7) << 4;
        *(short8*)(As + byte) = v;
    }
    if (tid < EPB) idxs[tid] = eidx[t * EE + e0 + tid];
    __syncthreads();

    // Coalesced pre-gather of the 32 needed sg rows into LDS (issued before
    // MFMA so the latency overlaps compute via TLP). 32 rows x 128 uint.
#pragma unroll
    for (int j = 0; j < 16; ++j) {
        const int item = j * 256 + tid;              // 4096 uint items
        const int row = item >> 7, c2 = item & 127;
        const uint v = *(const uint*)(sg + (size_t)idxs[row] * UU + c2 * 2);
        *(uint*)&sgl[row][c2 * 2] = v;
    }

    const short* Bg = WtGe + t * 32768;  // [256n][128k]
    const short* Bd = WtDe + t * 32768;
    const int nb = wid * 64;

    f32x4 accg[2][4], accv[2][4];
#pragma unroll
    for (int m = 0; m < 2; ++m)
#pragma unroll
        for (int n = 0; n < 4; ++n) {
            accg[m][n] = (f32x4){0.f, 0.f, 0.f, 0.f};
            accv[m][n] = (f32x4){0.f, 0.f, 0.f, 0.f};
        }

#pragma unroll
    for (int ks = 0; ks < 4; ++ks) {
        short8 a[2];
#pragma unroll
        for (int m = 0; m < 2; ++m) {
            const int row = m * 16 + (lane & 15);
            int byte = row * 256 + ks * 64 + (lane >> 4) * 16;
            byte ^= (row & 7) << 4;
            a[m] = *(const short8*)(As + byte);
        }
#pragma unroll
        for (int n = 0; n < 4; ++n) {
            const int col = nb + n * 16 + (lane & 15);
            const int koff = ks * 32 + (lane >> 4) * 8;
            const short8 bg = *(const short8*)(Bg + col * 128 + koff);
            const short8 bv = *(const short8*)(Bd + col * 128 + koff);
#pragma unroll
            for (int m = 0; m < 2; ++m) {
                accg[m][n] = __builtin_amdgcn_mfma_f32_16x16x32_bf16(a[m], bg, accg[m][n], 0, 0, 0);
                accv[m][n] = __builtin_amdgcn_mfma_f32_16x16x32_bf16(a[m], bv, accv[m][n], 0, 0, 0);
            }
        }
    }
    __syncthreads();  // sgl ready

    float bias[4];
#pragma unroll
    for (int n = 0; n < 4; ++n) bias[n] = bd[t * UU + nb + n * 16 + (lane & 15)];

#pragma unroll
    for (int m = 0; m < 2; ++m) {
        const int ebase = m * 16 + (lane >> 4) * 4;
        int node[4];
#pragma unroll
        for (int r = 0; r < 4; ++r) node[r] = idxs[ebase + r];
#pragma unroll
        for (int n = 0; n < 4; ++n) {
            const int col = nb + n * 16 + (lane & 15);
#pragma unroll
            for (int r = 0; r < 4; ++r) {
                const float sgv = bf2f(sgl[ebase + r][col]);
                const float g = 1.f / (1.f + __expf(-(sgv + accg[m][n][r])));
                const float msg = (accv[m][n][r] + bias[n]) * g;
                atomicAdd(&out[(size_t)node[r] * UU + col], msg);
            }
        }
    }
}

extern "C" void kernel_launch(void* const* d_in, const int* in_sizes, int n_in,
                              void* d_out, int out_size, void* d_ws, size_t ws_size,
                              hipStream_t stream) {
    const float* feats = (const float*)d_in[0];
    const int*   eidx  = (const int*)d_in[1];
    const float* efeat = (const float*)d_in[2];
    const float* Wg    = (const float*)d_in[3];
    const float* Wge   = (const float*)d_in[4];
    const float* Wde   = (const float*)d_in[5];
    const float* bd    = (const float*)d_in[6];
    float* out = (float*)d_out;

    // ws layout: sg bf16 (51.2 MB) | WtG (128 KB) | WtGe (192 KB) | WtDe (192 KB)
    char* ws = (char*)d_ws;
    ushort* sg = (ushort*)ws;
    const size_t sg_bytes = (size_t)M1 * UU * sizeof(ushort);
    short* WtG  = (short*)(ws + sg_bytes);
    short* WtGe = (short*)(ws + sg_bytes + 131072);
    short* WtDe = (short*)(ws + sg_bytes + 131072 + 196608);

    hipMemsetAsync(d_out, 0, (size_t)out_size * sizeof(float), stream);

    k_prep<<<262144 / 256, 256, 0, stream>>>(Wg, Wge, Wde, WtG, WtGe, WtDe);
    k1_srcgate<<<M1 / 32, 256, 0, stream>>>(feats, WtG, sg);
    k2_edges<<<dim3(EE / EPB, TT), 256, 0, stream>>>(eidx, efeat, WtGe, WtDe, bd,
                                                     (const ushort*)sg, out);
}